// Round 11
// baseline (367.050 us; speedup 1.0000x reference)
//
#include <hip/hip_runtime.h>

#define BATCH 4
#define SEQ   4096
#define NEMBD 384
#define HDIM  64
#define KBLK  64
// 64^-0.5 * log2(e): q pre-scaled so softmax works in exp2 domain
#define QSCALE 0.18033688011112042f
#define NEG_BIG (-1.0e30f)
#define DEFER_THR 8.0f
#define EXP2F(x) __builtin_amdgcn_exp2f(x)

typedef float f32x2 __attribute__((ext_vector_type(2)));

__device__ __forceinline__ f32x2 splat2(float s) { f32x2 r; r.x = s; r.y = s; return r; }
__device__ __forceinline__ f32x2 mk2(float a, float b) { f32x2 r; r.x = a; r.y = b; return r; }
__device__ __forceinline__ f32x2 fma2(f32x2 a, f32x2 b, f32x2 c) {
    return __builtin_elementwise_fma(a, b, c);
}

// ---------------- QKV projection v3: 16-row blocks, W reg-prefetch ----------
__global__ __launch_bounds__(256) void qkv_proj_kernel(
    const float* __restrict__ x,
    const float* __restrict__ Wq,
    const float* __restrict__ Wk,
    const float* __restrict__ Wv,
    float* __restrict__ q,
    float* __restrict__ k,
    float* __restrict__ v)
{
    __shared__ float xs[16][NEMBD];            // 24 KB -> 4+ blocks/CU
    const int tid  = threadIdx.x;
    const long row0 = (long)blockIdx.x * 16;

    {
        const float4* xg = (const float4*)(x + row0*NEMBD);
        float4* xl = (float4*)&xs[0][0];
#pragma unroll
        for (int i = 0; i < 6; ++i)
            xl[tid + i*256] = xg[tid + i*256];
    }
    __syncthreads();

    const int c  = tid & 63;
    const int rg = tid >> 6;                   // 0..3 -> 4 rows each
    float aq[4], ak[4], av[4];
#pragma unroll
    for (int r = 0; r < 4; ++r) { aq[r]=0.f; ak[r]=0.f; av[r]=0.f; }

    const float* pq = Wq + c;
    const float* pk = Wk + c;
    const float* pv = Wv + c;

    // software-pipelined W: current in wq/wk/wv, next prefetched each iter
    float wq[4], wk[4], wv[4];
#pragma unroll
    for (int jj = 0; jj < 4; ++jj) {
        wq[jj] = pq[jj*HDIM]; wk[jj] = pk[jj*HDIM]; wv[jj] = pv[jj*HDIM];
    }

#pragma unroll 2
    for (int k4 = 0; k4 < NEMBD/4; ++k4) {
        const int kk = k4*4;
        float nwq[4], nwk[4], nwv[4];
        if (k4 + 1 < NEMBD/4) {
#pragma unroll
            for (int jj = 0; jj < 4; ++jj) {
                nwq[jj] = pq[(kk+4+jj)*HDIM];
                nwk[jj] = pk[(kk+4+jj)*HDIM];
                nwv[jj] = pv[(kk+4+jj)*HDIM];
            }
        }
        float4 xr[4];
#pragma unroll
        for (int r = 0; r < 4; ++r)
            xr[r] = *(const float4*)&xs[rg*4 + r][kk];
#pragma unroll
        for (int jj = 0; jj < 4; ++jj) {
#pragma unroll
            for (int r = 0; r < 4; ++r) {
                const float xc = (jj==0)?xr[r].x:(jj==1)?xr[r].y:(jj==2)?xr[r].z:xr[r].w;
                aq[r] = fmaf(xc, wq[jj], aq[r]);
                ak[r] = fmaf(xc, wk[jj], ak[r]);
                av[r] = fmaf(xc, wv[jj], av[r]);
            }
        }
#pragma unroll
        for (int jj = 0; jj < 4; ++jj) { wq[jj]=nwq[jj]; wk[jj]=nwk[jj]; wv[jj]=nwv[jj]; }
    }
#pragma unroll
    for (int r = 0; r < 4; ++r) {
        const long o = (row0 + rg*4 + r)*HDIM + c;
        q[o] = aq[r];
        k[o] = ak[r];
        v[o] = av[r];
    }
}

// 8-lane sum reduce on the VALU via DPP (proven in v5): xor1, xor2, mirror.
__device__ __forceinline__ float red8(float x) {
    int t = __builtin_amdgcn_update_dpp(0, __float_as_int(x), 0xB1, 0xF, 0xF, true);
    x += __int_as_float(t);
    t = __builtin_amdgcn_update_dpp(0, __float_as_int(x), 0x4E, 0xF, 0xF, true);
    x += __int_as_float(t);
    t = __builtin_amdgcn_update_dpp(0, __float_as_int(x), 0x141, 0xF, 0xF, true);
    x += __int_as_float(t);
    return x;
}

// ---------------- causal flash attention v6: v5 + packed-fp32 pairs ---------
// Wave = 8 row-quads x 8 lanes. Lane owns rows r0..r0+3 (as 2 f32x2 pairs:
// pair p = rows r0+2p / r0+2p+1) and dims j8..j8+7. Dot/PV/rescale run on
// f32x2 -> v_pk_fma_f32/v_pk_mul_f32 (K/V broadcast via op_sel). red8 + exp
// stay scalar. Interleaved split-K S=16 for load balance.

#define DOT_PAIR(P, KA, KB, OUT)                                               \
    { f32x2 t = q2##P[0] * KA.x;                                               \
      t = fma2(q2##P[1], splat2(KA.y), t);                                     \
      t = fma2(q2##P[2], splat2(KA.z), t);                                     \
      t = fma2(q2##P[3], splat2(KA.w), t);                                     \
      t = fma2(q2##P[4], splat2(KB.x), t);                                     \
      t = fma2(q2##P[5], splat2(KB.y), t);                                     \
      t = fma2(q2##P[6], splat2(KB.z), t);                                     \
      t = fma2(q2##P[7], splat2(KB.w), t);                                     \
      OUT = t; }

#define KEYSTEP(MASKED)                                                        \
  {                                                                            \
    const float4 ka = *(const float4*)&Ks[kk][j8];                             \
    const float4 kb = *(const float4*)&Ks[kk][j8 + 4];                         \
    f32x2 a0, a1;                                                              \
    DOT_PAIR(0, ka, kb, a0)                                                    \
    DOT_PAIR(1, ka, kb, a1)                                                    \
    f32x2 s20 = mk2(red8(a0.x), red8(a0.y));                                   \
    f32x2 s21 = mk2(red8(a1.x), red8(a1.y));                                   \
    const f32x2 d0 = s20 - m20, d1 = s21 - m21;                                \
    const float cmax = fmaxf(fmaxf(d0.x, d0.y), fmaxf(d1.x, d1.y));            \
    if (__any(cmax > DEFER_THR)) {           /* rare */                        \
      f32x2 nm0 = __builtin_elementwise_max(m20, s20);                         \
      f32x2 nm1 = __builtin_elementwise_max(m21, s21);                         \
      f32x2 sc0 = mk2(EXP2F(m20.x - nm0.x), EXP2F(m20.y - nm0.y));             \
      f32x2 sc1 = mk2(EXP2F(m21.x - nm1.x), EXP2F(m21.y - nm1.y));             \
      m20 = nm0; m21 = nm1;                                                    \
      l20 = l20 * sc0; l21 = l21 * sc1;                                        \
      _Pragma("unroll")                                                        \
      for (int d = 0; d < 8; ++d) { o20[d] = o20[d]*sc0; o21[d] = o21[d]*sc1; }\
    }                                                                          \
    f32x2 pp0 = mk2(EXP2F(s20.x - m20.x), EXP2F(s20.y - m20.y));               \
    f32x2 pp1 = mk2(EXP2F(s21.x - m21.x), EXP2F(s21.y - m21.y));               \
    if (MASKED) {                                                              \
      const int doff = base + kk - r0;       /* key - first row */             \
      pp0.x = (doff <= 0) ? pp0.x : 0.f;                                       \
      pp0.y = (doff <= 1) ? pp0.y : 0.f;                                       \
      pp1.x = (doff <= 2) ? pp1.x : 0.f;                                       \
      pp1.y = (doff <= 3) ? pp1.y : 0.f;                                       \
    }                                                                          \
    l20 += pp0; l21 += pp1;                                                    \
    const float4 va = *(const float4*)&Vs[kk][j8];                             \
    const float4 vb = *(const float4*)&Vs[kk][j8 + 4];                         \
    o20[0] = fma2(pp0, splat2(va.x), o20[0]);                                  \
    o20[1] = fma2(pp0, splat2(va.y), o20[1]);                                  \
    o20[2] = fma2(pp0, splat2(va.z), o20[2]);                                  \
    o20[3] = fma2(pp0, splat2(va.w), o20[3]);                                  \
    o20[4] = fma2(pp0, splat2(vb.x), o20[4]);                                  \
    o20[5] = fma2(pp0, splat2(vb.y), o20[5]);                                  \
    o20[6] = fma2(pp0, splat2(vb.z), o20[6]);                                  \
    o20[7] = fma2(pp0, splat2(vb.w), o20[7]);                                  \
    o21[0] = fma2(pp1, splat2(va.x), o21[0]);                                  \
    o21[1] = fma2(pp1, splat2(va.y), o21[1]);                                  \
    o21[2] = fma2(pp1, splat2(va.z), o21[2]);                                  \
    o21[3] = fma2(pp1, splat2(va.w), o21[3]);                                  \
    o21[4] = fma2(pp1, splat2(vb.x), o21[4]);                                  \
    o21[5] = fma2(pp1, splat2(vb.y), o21[5]);                                  \
    o21[6] = fma2(pp1, splat2(vb.z), o21[6]);                                  \
    o21[7] = fma2(pp1, splat2(vb.w), o21[7]);                                  \
  }

__global__ __launch_bounds__(256, 4) void attn_kernel(
    const float* __restrict__ Q,
    const float* __restrict__ K,
    const float* __restrict__ V,
    float* __restrict__ opart,
    float* __restrict__ mlpart,
    const int S)
{
    __shared__ float Ks[KBLK][HDIM];
    __shared__ float Vs[KBLK][HDIM];

    const int gid  = blockIdx.x;
    const int part = gid % S;
    const int rest = gid / S;
    const int b    = rest & 3;
    const int qt   = 31 - (rest >> 2);      // 128-row tile, longest first
    const int q0   = qt * 128;
    const int tid  = threadIdx.x;
    const int w    = tid >> 6;              // wave 0..3
    const int lane = tid & 63;
    const int g    = lane >> 3;             // row-quad 0..7
    const int j8   = (lane & 7) * 8;        // dim octet base
    const int Rw   = q0 + w*32;             // wave's first row
    const int r0   = Rw + g*4;              // lane's first row
    const int wmax = Rw + 31;

    // q fragments: 2 row-pairs x 8 dims, f32x2 (x=even row, y=odd row)
    f32x2 q20[8], q21[8];
    {
        const float* qp = Q + ((long)b*SEQ + r0)*HDIM + j8;
        const float4 A0 = *(const float4*)(qp);
        const float4 B0 = *(const float4*)(qp + 4);
        const float4 A1 = *(const float4*)(qp + HDIM);
        const float4 B1 = *(const float4*)(qp + HDIM + 4);
        const float4 A2 = *(const float4*)(qp + 2*HDIM);
        const float4 B2 = *(const float4*)(qp + 2*HDIM + 4);
        const float4 A3 = *(const float4*)(qp + 3*HDIM);
        const float4 B3 = *(const float4*)(qp + 3*HDIM + 4);
        q20[0] = mk2(A0.x, A1.x) * QSCALE; q20[1] = mk2(A0.y, A1.y) * QSCALE;
        q20[2] = mk2(A0.z, A1.z) * QSCALE; q20[3] = mk2(A0.w, A1.w) * QSCALE;
        q20[4] = mk2(B0.x, B1.x) * QSCALE; q20[5] = mk2(B0.y, B1.y) * QSCALE;
        q20[6] = mk2(B0.z, B1.z) * QSCALE; q20[7] = mk2(B0.w, B1.w) * QSCALE;
        q21[0] = mk2(A2.x, A3.x) * QSCALE; q21[1] = mk2(A2.y, A3.y) * QSCALE;
        q21[2] = mk2(A2.z, A3.z) * QSCALE; q21[3] = mk2(A2.w, A3.w) * QSCALE;
        q21[4] = mk2(B2.x, B3.x) * QSCALE; q21[5] = mk2(B2.y, B3.y) * QSCALE;
        q21[6] = mk2(B2.z, B3.z) * QSCALE; q21[7] = mk2(B2.w, B3.w) * QSCALE;
    }
    f32x2 o20[8], o21[8];
    f32x2 m20 = splat2(NEG_BIG), m21 = splat2(NEG_BIG);
    f32x2 l20 = splat2(0.f),     l21 = splat2(0.f);
#pragma unroll
    for (int d = 0; d < 8; ++d) { o20[d] = splat2(0.f); o21[d] = splat2(0.f); }

    const float* Kb = K + (long)b*SEQ*HDIM;
    const float* Vb = V + (long)b*SEQ*HDIM;
    const int ntiles = (q0 + 128) / KBLK;   // 2*(qt+1), block-uniform

    for (int kt = part; kt < ntiles; kt += S) {
        __syncthreads();
        {
            const float4* Kg = (const float4*)(Kb + (long)kt*KBLK*HDIM);
            const float4* Vg = (const float4*)(Vb + (long)kt*KBLK*HDIM);
            float4* Ksw = (float4*)&Ks[0][0];
            float4* Vsw = (float4*)&Vs[0][0];
#pragma unroll
            for (int i = 0; i < 4; ++i) {
                Ksw[tid + i*256] = Kg[tid + i*256];
                Vsw[tid + i*256] = Vg[tid + i*256];
            }
        }
        __syncthreads();

        const int base = kt * KBLK;
        if (base > wmax) continue;          // wave idle for this tile

        if (base + KBLK <= Rw) {
            for (int kk = 0; kk < KBLK; ++kk) KEYSTEP(false)
        } else {
            const int kkend = Rw + 32 - base;   // max lim over the wave
            for (int kk = 0; kk < kkend; ++kk) KEYSTEP(true)
        }
    }

    const long PERM = (long)BATCH * SEQ;
    const long obase = ((long)part*PERM + (long)b*SEQ + r0)*HDIM + j8;
    {
        float4 ra, rb;
        ra.x = o20[0].x; ra.y = o20[1].x; ra.z = o20[2].x; ra.w = o20[3].x;
        rb.x = o20[4].x; rb.y = o20[5].x; rb.z = o20[6].x; rb.w = o20[7].x;
        *(float4*)(opart + obase)              = ra;
        *(float4*)(opart + obase + 4)          = rb;
        ra.x = o20[0].y; ra.y = o20[1].y; ra.z = o20[2].y; ra.w = o20[3].y;
        rb.x = o20[4].y; rb.y = o20[5].y; rb.z = o20[6].y; rb.w = o20[7].y;
        *(float4*)(opart + obase + HDIM)       = ra;
        *(float4*)(opart + obase + HDIM + 4)   = rb;
        ra.x = o21[0].x; ra.y = o21[1].x; ra.z = o21[2].x; ra.w = o21[3].x;
        rb.x = o21[4].x; rb.y = o21[5].x; rb.z = o21[6].x; rb.w = o21[7].x;
        *(float4*)(opart + obase + 2*HDIM)     = ra;
        *(float4*)(opart + obase + 2*HDIM + 4) = rb;
        ra.x = o21[0].y; ra.y = o21[1].y; ra.z = o21[2].y; ra.w = o21[3].y;
        rb.x = o21[4].y; rb.y = o21[5].y; rb.z = o21[6].y; rb.w = o21[7].y;
        *(float4*)(opart + obase + 3*HDIM)     = ra;
        *(float4*)(opart + obase + 3*HDIM + 4) = rb;
    }
    if (j8 == 0) {
        float2 ml;
        ml.x = m20.x; ml.y = l20.x;
        *(float2*)&mlpart[((long)part*PERM + (long)b*SEQ + r0 + 0)*2] = ml;
        ml.x = m20.y; ml.y = l20.y;
        *(float2*)&mlpart[((long)part*PERM + (long)b*SEQ + r0 + 1)*2] = ml;
        ml.x = m21.x; ml.y = l21.x;
        *(float2*)&mlpart[((long)part*PERM + (long)b*SEQ + r0 + 2)*2] = ml;
        ml.x = m21.y; ml.y = l21.y;
        *(float2*)&mlpart[((long)part*PERM + (long)b*SEQ + r0 + 3)*2] = ml;
    }
}

// ---------------- split-K combine (S parts, exp2 domain) ----------------
__global__ __launch_bounds__(256) void combine_kernel(
    const float* __restrict__ opart,
    const float* __restrict__ mlpart,
    float* __restrict__ out,
    const int S)
{
    const int tid  = threadIdx.x;
    const int d    = tid & 63;
    const int rsub = tid >> 6;                      // 0..3
    const long row = (long)blockIdx.x * 4 + rsub;
    const long PERO = (long)BATCH * SEQ * HDIM;
    const long PERM = (long)BATCH * SEQ;

    float M = NEG_BIG;
    for (int p = 0; p < S; ++p)
        M = fmaxf(M, mlpart[((long)p*PERM + row)*2]);

    float L = 0.f, acc = 0.f;
    for (int p = 0; p < S; ++p) {
        const float2 ml = *(const float2*)&mlpart[((long)p*PERM + row)*2];
        const float e = EXP2F(ml.x - M);            // 0 for empty parts
        L   = fmaf(ml.y, e, L);
        acc = fmaf(opart[(long)p*PERO + row*HDIM + d], e, acc);
    }
    out[row*HDIM + d] = acc / L;
}

extern "C" void kernel_launch(void* const* d_in, const int* in_sizes, int n_in,
                              void* d_out, int out_size, void* d_ws, size_t ws_size,
                              hipStream_t stream) {
    const float* x  = (const float*)d_in[0];
    const float* Wq = (const float*)d_in[1];
    const float* Wk = (const float*)d_in[2];
    const float* Wv = (const float*)d_in[3];
    float* out = (float*)d_out;

    const size_t PER  = (size_t)BATCH * SEQ * HDIM;   // 1M floats
    const size_t PERM = (size_t)BATCH * SEQ;          // 16K rows

    int S = 16;
    while (S > 1 && (3*PER + (size_t)S*PER + (size_t)S*PERM*2)*4 > ws_size) S >>= 1;

    float* qws    = (float*)d_ws;
    float* kws    = qws + PER;
    float* vws    = kws + PER;
    float* opart  = vws + PER;                 // S * PER floats
    float* mlpart = opart + (size_t)S*PER;     // S * PERM * 2 floats

    qkv_proj_kernel<<<BATCH*SEQ/16, 256, 0, stream>>>(x, Wq, Wk, Wv, qws, kws, vws);
    attn_kernel<<<S*BATCH*(SEQ/128), 256, 0, stream>>>(qws, kws, vws, opart, mlpart, S);
    combine_kernel<<<BATCH*SEQ/4, 256, 0, stream>>>(opart, mlpart, out, S);
}